// Round 8
// baseline (915.729 us; speedup 1.0000x reference)
//
#include <hip/hip_runtime.h>

static constexpr int NN = 100000;   // nodes
static constexpr int NE = 500000;   // edges
static constexpr int D  = 32;       // channels
static constexpr int NR = 16;       // relations
static constexpr int HB = 256;      // histogram / scatter blocks
static constexpr int ES = (NE + HB - 1) / HB;   // edges per hist/scatter block
static constexpr int NY = 96;       // blocks per type in k_edge -> 1536 blocks

// ---------------- K1: h = x @ W  (+ hist + d_out zeroing) ---------------
__global__ __launch_bounds__(256) void k_xw_hist(const float* __restrict__ x,
                                                 const float* __restrict__ W,
                                                 const int* __restrict__ et,
                                                 float* __restrict__ h,
                                                 int* __restrict__ cnt,
                                                 float* __restrict__ outz) {
    __shared__ float sW[D * D];
    __shared__ int lh[NR];
    if (threadIdx.x < NR) lh[threadIdx.x] = 0;
    for (int i = threadIdx.x; i < D * D; i += 256) sW[i] = W[i];
    __syncthreads();

    {   // zero d_out (grid-stride) — replaces the 12.8 MB memset dispatch
        float4* oz = reinterpret_cast<float4*>(outz);
        const int total4 = NN * D / 4;
        for (int i = blockIdx.x * 256 + threadIdx.x; i < total4; i += gridDim.x * 256)
            oz[i] = make_float4(0.f, 0.f, 0.f, 0.f);
    }

    if (blockIdx.x < HB) {   // 256 blocks histogram -> 4096 global atomics
        const int beg = blockIdx.x * ES, end = min(beg + ES, NE);
        for (int e = beg + (int)threadIdx.x; e < end; e += 256)
            atomicAdd(&lh[et[e]], 1);
    }

    const int n = blockIdx.x * 256 + threadIdx.x;
    if (n < NN) {
        float xr[D];
        const float4* xv = reinterpret_cast<const float4*>(x + (size_t)n * D);
        #pragma unroll
        for (int k = 0; k < 8; ++k) {
            float4 v = xv[k];
            xr[4*k+0] = v.x; xr[4*k+1] = v.y; xr[4*k+2] = v.z; xr[4*k+3] = v.w;
        }
        float4* hv = reinterpret_cast<float4*>(h + (size_t)n * D);
        #pragma unroll
        for (int oc = 0; oc < 8; ++oc) {
            float a0 = 0.f, a1 = 0.f, a2 = 0.f, a3 = 0.f;
            #pragma unroll
            for (int i = 0; i < D; ++i) {
                float xi = xr[i];
                a0 += xi * sW[i*D + 4*oc + 0];
                a1 += xi * sW[i*D + 4*oc + 1];
                a2 += xi * sW[i*D + 4*oc + 2];
                a3 += xi * sW[i*D + 4*oc + 3];
            }
            hv[oc] = make_float4(a0, a1, a2, a3);
        }
    }
    __syncthreads();
    if (blockIdx.x < HB && threadIdx.x < NR && lh[threadIdx.x] > 0)
        atomicAdd(&cnt[threadIdx.x], lh[threadIdx.x]);
}

// ---------------- K2a: scatter into type buckets (range-grab) -----------
__global__ __launch_bounds__(256) void k_scatter(const int* __restrict__ ei,
                                                 const int* __restrict__ et,
                                                 const int* __restrict__ cnt,
                                                 int* __restrict__ cursor,
                                                 int2* __restrict__ rec) {
    __shared__ int lh[NR], lcur[NR], soff[NR];
    if (threadIdx.x < NR) lh[threadIdx.x] = 0;
    if (threadIdx.x == 0) {
        int s = 0;
        for (int t = 0; t < NR; ++t) { soff[t] = s; s += cnt[t]; }
    }
    __syncthreads();
    const int beg = blockIdx.x * ES, end = min(beg + ES, NE);
    for (int e = beg + (int)threadIdx.x; e < end; e += 256)
        atomicAdd(&lh[et[e]], 1);
    __syncthreads();
    if (threadIdx.x < NR)
        lcur[threadIdx.x] = (lh[threadIdx.x] > 0)
                          ? soff[threadIdx.x] + atomicAdd(&cursor[threadIdx.x], lh[threadIdx.x])
                          : 0;
    __syncthreads();
    for (int e = beg + (int)threadIdx.x; e < end; e += 256) {
        const int t = et[e];
        const int pos = atomicAdd(&lcur[t], 1);
        rec[pos] = make_int2(ei[e], ei[NE + e]);
    }
}

// ---------------- K2b: per-edge matvec + scatter-add (lane = edge) ------
// Whole wave shares one relation type t (edges are type-sorted). Each lane
// owns one edge: h-row gathered into 32 VGPRs; R_t[i][o] is wave-uniform
// -> scalar loads (K$-cached, 4 KB) feeding v_fma's SGPR operand. No LDS,
// 16 FMA-instr/edge minimum, full 64-lane utilization.
__global__ __launch_bounds__(256) void k_edge(const float* __restrict__ h,
                                              const int2* __restrict__ rec,
                                              const int* __restrict__ cnt,
                                              const float* __restrict__ rel,
                                              float* __restrict__ acc) {
    const int t = blockIdx.x & (NR - 1);
    const int c = blockIdx.x >> 4;            // 0..NY-1
    const int lane = threadIdx.x & 63;
    const int wv = threadIdx.x >> 6;          // wave in block 0..3
    const float* __restrict__ Rt = rel + t * 1024;   // wave-uniform

    int beg = 0;
    #pragma unroll
    for (int u = 0; u < NR; ++u) beg += (u < t) ? cnt[u] : 0;
    const int cntt = cnt[t];
    if (cntt <= 0) return;

    const int nw   = NY * 4;                  // waves per type
    const int wid  = c * 4 + wv;
    const int ngrp = (cntt + 63) >> 6;        // 64-edge groups
    const int gpw  = (ngrp + nw - 1) / nw;
    const int g0   = wid * gpw;
    const int g1   = min(g0 + gpw, ngrp);

    const int elast = beg + cntt - 1;
    for (int g = g0; g < g1; ++g) {
        const int e = beg + g * 64 + lane;
        const bool valid = (e <= elast);
        const int2 rr = rec[valid ? e : elast];

        float hs[32];
        {
            const float4* hp = reinterpret_cast<const float4*>(h + (size_t)rr.x * D);
            #pragma unroll
            for (int q = 0; q < 8; ++q) {
                const float4 v = hp[q];
                hs[4*q+0] = v.x; hs[4*q+1] = v.y; hs[4*q+2] = v.z; hs[4*q+3] = v.w;
            }
        }
        float a[32];
        #pragma unroll
        for (int o = 0; o < 32; ++o) a[o] = 0.f;
        #pragma unroll
        for (int i = 0; i < 32; ++i) {
            const float hi = hs[i];
            #pragma unroll
            for (int o = 0; o < 32; ++o)
                a[o] = fmaf(hi, Rt[i * 32 + o], a[o]);
        }
        if (valid) {
            float* op = acc + (size_t)rr.y * D;
            #pragma unroll
            for (int o = 0; o < 32; ++o)
                atomicAdd(op + o, a[o]);
        }
    }
}

// ---------------- K3a: scores + per-block online (max, sum-exp) ---------
__global__ __launch_bounds__(256) void k_score(const float* __restrict__ acc,
                                               const float* __restrict__ att,
                                               float* __restrict__ scores,
                                               float* __restrict__ pmax,
                                               float* __restrict__ psum) {
    __shared__ float sA[D];
    __shared__ float shm[4], shs[4];
    if (threadIdx.x < D) sA[threadIdx.x] = att[threadIdx.x];
    __syncthreads();
    const int n = blockIdx.x * 256 + threadIdx.x;
    float s = -3.4e38f;
    if (n < NN) {
        const float4* av = reinterpret_cast<const float4*>(acc + (size_t)n * D);
        float v0 = 0.f;
        #pragma unroll
        for (int k = 0; k < 8; ++k) {
            float4 v = av[k];
            v0 += v.x * sA[4*k+0] + v.y * sA[4*k+1] + v.z * sA[4*k+2] + v.w * sA[4*k+3];
        }
        scores[n] = v0;
        s = v0;
    }
    float m = s;
    #pragma unroll
    for (int offt = 32; offt > 0; offt >>= 1)
        m = fmaxf(m, __shfl_down(m, offt, 64));
    if ((threadIdx.x & 63) == 0) shm[threadIdx.x >> 6] = m;
    __syncthreads();
    const float bm = fmaxf(fmaxf(shm[0], shm[1]), fmaxf(shm[2], shm[3]));
    float e = (n < NN) ? expf(s - bm) : 0.f;
    #pragma unroll
    for (int offt = 32; offt > 0; offt >>= 1)
        e += __shfl_down(e, offt, 64);
    if ((threadIdx.x & 63) == 0) shs[threadIdx.x >> 6] = e;
    __syncthreads();
    if (threadIdx.x == 0) {
        pmax[blockIdx.x] = bm;
        psum[blockIdx.x] = shs[0] + shs[1] + shs[2] + shs[3];
    }
}

// ---------------- K3b: fused combine + scale ----------------------------
__global__ __launch_bounds__(256) void k_final(float* __restrict__ out,
                                               const float* __restrict__ scores,
                                               const float* __restrict__ pmax,
                                               const float* __restrict__ psum,
                                               int nb) {
    __shared__ float shm[4], shs[4];
    const int tid = threadIdx.x;
    float m = -3.4e38f, s = 0.f;
    for (int i = tid; i < nb; i += 256) {
        const float mi = pmax[i], si = psum[i];
        const float M = fmaxf(m, mi);
        s = s * expf(m - M) + si * expf(mi - M);
        m = M;
    }
    #pragma unroll
    for (int offt = 32; offt > 0; offt >>= 1) {
        const float mo = __shfl_down(m, offt, 64);
        const float so = __shfl_down(s, offt, 64);
        const float M = fmaxf(m, mo);
        s = s * expf(m - M) + so * expf(mo - M);
        m = M;
    }
    if ((tid & 63) == 0) { shm[tid >> 6] = m; shs[tid >> 6] = s; }
    __syncthreads();
    float M = shm[0], S = shs[0];
    #pragma unroll
    for (int w = 1; w < 4; ++w) {
        const float Mn = fmaxf(M, shm[w]);
        S = S * expf(M - Mn) + shs[w] * expf(shm[w] - Mn);
        M = Mn;
    }
    const int idx = blockIdx.x * 256 + tid;        // float4 index, exact grid
    const int n = idx >> 3;
    const float w = expf(scores[n] - M) / S;
    float4* p = reinterpret_cast<float4*>(out);
    float4 v = p[idx];
    v.x = fmaxf(v.x * w, 0.f);
    v.y = fmaxf(v.y * w, 0.f);
    v.z = fmaxf(v.z * w, 0.f);
    v.w = fmaxf(v.w * w, 0.f);
    p[idx] = v;
}

extern "C" void kernel_launch(void* const* d_in, const int* in_sizes, int n_in,
                              void* d_out, int out_size, void* d_ws, size_t ws_size,
                              hipStream_t stream) {
    const float* x   = (const float*)d_in[0];
    const int*   ei  = (const int*)  d_in[1];
    const int*   et  = (const int*)  d_in[2];
    const float* W   = (const float*)d_in[3];
    const float* rel = (const float*)d_in[4];
    const float* att = (const float*)d_in[5];
    float* out = (float*)d_out;

    // ws layout: h[NN*D] | rec[NE int2] | cnt[16] | cursor[16]
    //            | pmax[512] | psum[512];  scores overlays rec after k_edge
    float* h      = (float*)d_ws;
    int2*  rec    = (int2*)(h + (size_t)NN * D);
    int*   cnt    = (int*)(rec + NE);
    int*   cursor = cnt + NR;
    float* pmax   = (float*)(cursor + NR);
    float* psum   = pmax + 512;
    float* scores = (float*)rec;

    hipMemsetAsync(cnt, 0, 2 * NR * sizeof(int), stream);   // cnt + cursor

    const int nb_n = (NN + 255) / 256;           // 391
    k_xw_hist<<<nb_n, 256, 0, stream>>>(x, W, et, h, cnt, out);
    k_scatter<<<HB, 256, 0, stream>>>(ei, et, cnt, cursor, rec);
    k_edge<<<NR * NY, 256, 0, stream>>>(h, rec, cnt, rel, out);
    k_score<<<nb_n, 256, 0, stream>>>(out, att, scores, pmax, psum);
    k_final<<<(NN * (D / 4)) / 256, 256, 0, stream>>>(out, scores, pmax, psum, nb_n);
}

// Round 9
// 170.736 us; speedup vs baseline: 5.3634x; 5.3634x over previous
//
#include <hip/hip_runtime.h>

static constexpr int NN = 100000;   // nodes
static constexpr int NE = 500000;   // edges
static constexpr int D  = 32;       // channels
static constexpr int NR = 16;       // relations
static constexpr int HB = 256;      // histogram / scatter blocks
static constexpr int ES = (NE + HB - 1) / HB;   // edges per hist/scatter block
static constexpr int NY = 64;       // chunk blocks per type in k_edge -> 1024 blocks

// ---------------- K1: zero d_out + edge-type histogram + WR = W @ R_t ----
// blocks 0..HB-1: histogram slice + share of d_out zeroing
// block HB: also computes the 16 folded matrices WR[t] = W @ R_t
__global__ __launch_bounds__(256) void k_pre(const int* __restrict__ et,
                                             const float* __restrict__ W,
                                             const float* __restrict__ rel,
                                             float* __restrict__ wr,
                                             int* __restrict__ cnt,
                                             float* __restrict__ outz) {
    __shared__ int lh[NR];
    if (threadIdx.x < NR) lh[threadIdx.x] = 0;
    __syncthreads();

    {   // zero d_out (grid-stride over all blocks)
        float4* oz = reinterpret_cast<float4*>(outz);
        const int total4 = NN * D / 4;
        for (int i = blockIdx.x * 256 + threadIdx.x; i < total4; i += gridDim.x * 256)
            oz[i] = make_float4(0.f, 0.f, 0.f, 0.f);
    }

    if (blockIdx.x < HB) {
        const int beg = blockIdx.x * ES, end = min(beg + ES, NE);
        for (int e = beg + (int)threadIdx.x; e < end; e += 256)
            atomicAdd(&lh[et[e]], 1);
    } else {
        // WR[t][k][o] = sum_j W[k][j] * rel[t][j][o]
        for (int idx = threadIdx.x; idx < NR * D * D; idx += 256) {
            const int t = idx >> 10;
            const int k = (idx >> 5) & 31;
            const int o = idx & 31;
            const float* Wr = W + k * D;
            const float* Rr = rel + t * (D * D) + o;
            float s = 0.f;
            #pragma unroll
            for (int j = 0; j < D; ++j)
                s = fmaf(Wr[j], Rr[j * D], s);
            wr[idx] = s;
        }
    }
    __syncthreads();
    if (blockIdx.x < HB && threadIdx.x < NR && lh[threadIdx.x] > 0)
        atomicAdd(&cnt[threadIdx.x], lh[threadIdx.x]);
}

// ---------------- K2a: scatter into type buckets (range-grab) -----------
__global__ __launch_bounds__(256) void k_scatter(const int* __restrict__ ei,
                                                 const int* __restrict__ et,
                                                 const int* __restrict__ cnt,
                                                 int* __restrict__ cursor,
                                                 int2* __restrict__ rec) {
    __shared__ int lh[NR], lcur[NR], soff[NR];
    if (threadIdx.x < NR) lh[threadIdx.x] = 0;
    if (threadIdx.x == 0) {
        int s = 0;
        for (int t = 0; t < NR; ++t) { soff[t] = s; s += cnt[t]; }
    }
    __syncthreads();
    const int beg = blockIdx.x * ES, end = min(beg + ES, NE);
    for (int e = beg + (int)threadIdx.x; e < end; e += 256)
        atomicAdd(&lh[et[e]], 1);
    __syncthreads();
    if (threadIdx.x < NR)
        lcur[threadIdx.x] = (lh[threadIdx.x] > 0)
                          ? soff[threadIdx.x] + atomicAdd(&cursor[threadIdx.x], lh[threadIdx.x])
                          : 0;
    __syncthreads();
    for (int e = beg + (int)threadIdx.x; e < end; e += 256) {
        const int t = et[e];
        const int pos = atomicAdd(&lcur[t], 1);
        rec[pos] = make_int2(ei[e], ei[NE + e]);
    }
}

// ---------------- K2b: per-edge matvec + scatter-add --------------------
// lane = edge: each lane gathers its x-row into 8 named float4s and runs
// msg = x_row @ WR_t with WR_t wave-uniform (scalar loads from K$).
// Output channels in 4 chunks of 8 named accumulators (low VGPR, no
// spillable arrays). Results transposed through an XOR-swizzled per-wave
// LDS slab so the atomic phase is the proven coalesced half-wave 128B
// pattern (round-8's uncoalesced per-lane atomics were 8x write traffic).
#define COMP8(HX, ROW)                                                   \
    a0 = fmaf((HX), Rc[(ROW)*32 + 0], a0);                               \
    a1 = fmaf((HX), Rc[(ROW)*32 + 1], a1);                               \
    a2 = fmaf((HX), Rc[(ROW)*32 + 2], a2);                               \
    a3 = fmaf((HX), Rc[(ROW)*32 + 3], a3);                               \
    a4 = fmaf((HX), Rc[(ROW)*32 + 4], a4);                               \
    a5 = fmaf((HX), Rc[(ROW)*32 + 5], a5);                               \
    a6 = fmaf((HX), Rc[(ROW)*32 + 6], a6);                               \
    a7 = fmaf((HX), Rc[(ROW)*32 + 7], a7);

#define ROW4(V, I0) COMP8((V).x, I0) COMP8((V).y, (I0)+1) \
                    COMP8((V).z, (I0)+2) COMP8((V).w, (I0)+3)

#define CHUNK(OC)                                                        \
    {                                                                    \
        float a0=0.f,a1=0.f,a2=0.f,a3=0.f,a4=0.f,a5=0.f,a6=0.f,a7=0.f;   \
        const float* __restrict__ Rc = Rt + (OC) * 8;                    \
        ROW4(h0, 0)  ROW4(h1, 4)  ROW4(h2, 8)  ROW4(h3, 12)              \
        ROW4(h4, 16) ROW4(h5, 20) ROW4(h6, 24) ROW4(h7, 28)              \
        const int sx = lane & 31;                                        \
        smv[wv][lane][((OC)*8 + 0) ^ sx] = a0;                           \
        smv[wv][lane][((OC)*8 + 1) ^ sx] = a1;                           \
        smv[wv][lane][((OC)*8 + 2) ^ sx] = a2;                           \
        smv[wv][lane][((OC)*8 + 3) ^ sx] = a3;                           \
        smv[wv][lane][((OC)*8 + 4) ^ sx] = a4;                           \
        smv[wv][lane][((OC)*8 + 5) ^ sx] = a5;                           \
        smv[wv][lane][((OC)*8 + 6) ^ sx] = a6;                           \
        smv[wv][lane][((OC)*8 + 7) ^ sx] = a7;                           \
    }

__global__ __launch_bounds__(256, 2) void k_edge(const float* __restrict__ x,
                                                 const int2* __restrict__ rec,
                                                 const int* __restrict__ cnt,
                                                 const float* __restrict__ wr,
                                                 float* __restrict__ acc) {
    const int t  = blockIdx.x & (NR - 1);
    const int c  = blockIdx.x >> 4;           // 0..NY-1
    const int lane = threadIdx.x & 63;
    const int wv   = threadIdx.x >> 6;        // wave in block 0..3
    __shared__ float smv[4][64][32];          // 32 KB value transpose (XOR swz)
    __shared__ int   smd[4][64];              // 1 KB dst per slot
    const float* __restrict__ Rt = wr + t * 1024;   // wave-uniform

    int beg = 0;
    #pragma unroll
    for (int u = 0; u < NR; ++u) beg += (u < t) ? cnt[u] : 0;
    const int cntt = cnt[t];
    if (cntt <= 0) return;
    const int elast = beg + cntt - 1;
    const int ntile = (cntt + 63) >> 6;
    const int nw    = NY * 4;
    const int wid   = c * 4 + wv;

    for (int tile = wid; tile < ntile; tile += nw) {
        const int tbase = beg + tile * 64;
        const int e = tbase + lane;
        const int2 rr = rec[min(e, elast)];
        smd[wv][lane] = rr.y;

        const float4* __restrict__ xp =
            reinterpret_cast<const float4*>(x + (size_t)rr.x * D);
        const float4 h0 = xp[0], h1 = xp[1], h2 = xp[2], h3 = xp[3];
        const float4 h4 = xp[4], h5 = xp[5], h6 = xp[6], h7 = xp[7];

        CHUNK(0) CHUNK(1) CHUNK(2) CHUNK(3)

        __asm__ volatile("s_waitcnt lgkmcnt(0)" ::: "memory");

        // atomic phase: half-wave per edge, coalesced 128B regions
        const int g2 = lane >> 5, o = lane & 31;
        if (tbase + 63 <= elast) {            // full tile, no guards
            #pragma unroll
            for (int ep = 0; ep < 64; ep += 2) {
                const int eslot = ep + g2;
                const float v = smv[wv][eslot][o ^ (eslot & 31)];
                const int  dd = smd[wv][eslot];
                atomicAdd(acc + (size_t)dd * D + o, v);
            }
        } else {                              // tail tile
            #pragma unroll
            for (int ep = 0; ep < 64; ep += 2) {
                const int eslot = ep + g2;
                if (tbase + eslot <= elast) {
                    const float v = smv[wv][eslot][o ^ (eslot & 31)];
                    const int  dd = smd[wv][eslot];
                    atomicAdd(acc + (size_t)dd * D + o, v);
                }
            }
        }
        __asm__ volatile("" ::: "memory");
    }
}

// ---------------- K3a: scores + per-block online (max, sum-exp) ---------
__global__ __launch_bounds__(256) void k_score(const float* __restrict__ acc,
                                               const float* __restrict__ att,
                                               float* __restrict__ scores,
                                               float* __restrict__ pmax,
                                               float* __restrict__ psum) {
    __shared__ float sA[D];
    __shared__ float shm[4], shs[4];
    if (threadIdx.x < D) sA[threadIdx.x] = att[threadIdx.x];
    __syncthreads();
    const int n = blockIdx.x * 256 + threadIdx.x;
    float s = -3.4e38f;
    if (n < NN) {
        const float4* av = reinterpret_cast<const float4*>(acc + (size_t)n * D);
        float v0 = 0.f;
        #pragma unroll
        for (int k = 0; k < 8; ++k) {
            float4 v = av[k];
            v0 += v.x * sA[4*k+0] + v.y * sA[4*k+1] + v.z * sA[4*k+2] + v.w * sA[4*k+3];
        }
        scores[n] = v0;
        s = v0;
    }
    float m = s;
    #pragma unroll
    for (int offt = 32; offt > 0; offt >>= 1)
        m = fmaxf(m, __shfl_down(m, offt, 64));
    if ((threadIdx.x & 63) == 0) shm[threadIdx.x >> 6] = m;
    __syncthreads();
    const float bm = fmaxf(fmaxf(shm[0], shm[1]), fmaxf(shm[2], shm[3]));
    float e = (n < NN) ? expf(s - bm) : 0.f;
    #pragma unroll
    for (int offt = 32; offt > 0; offt >>= 1)
        e += __shfl_down(e, offt, 64);
    if ((threadIdx.x & 63) == 0) shs[threadIdx.x >> 6] = e;
    __syncthreads();
    if (threadIdx.x == 0) {
        pmax[blockIdx.x] = bm;
        psum[blockIdx.x] = shs[0] + shs[1] + shs[2] + shs[3];
    }
}

// ---------------- K3b: fused combine + scale ----------------------------
__global__ __launch_bounds__(256) void k_final(float* __restrict__ out,
                                               const float* __restrict__ scores,
                                               const float* __restrict__ pmax,
                                               const float* __restrict__ psum,
                                               int nb) {
    __shared__ float shm[4], shs[4];
    const int tid = threadIdx.x;
    float m = -3.4e38f, s = 0.f;
    for (int i = tid; i < nb; i += 256) {
        const float mi = pmax[i], si = psum[i];
        const float M = fmaxf(m, mi);
        s = s * expf(m - M) + si * expf(mi - M);
        m = M;
    }
    #pragma unroll
    for (int offt = 32; offt > 0; offt >>= 1) {
        const float mo = __shfl_down(m, offt, 64);
        const float so = __shfl_down(s, offt, 64);
        const float M = fmaxf(m, mo);
        s = s * expf(m - M) + so * expf(mo - M);
        m = M;
    }
    if ((tid & 63) == 0) { shm[tid >> 6] = m; shs[tid >> 6] = s; }
    __syncthreads();
    float M = shm[0], S = shs[0];
    #pragma unroll
    for (int w = 1; w < 4; ++w) {
        const float Mn = fmaxf(M, shm[w]);
        S = S * expf(M - Mn) + shs[w] * expf(shm[w] - Mn);
        M = Mn;
    }
    const int idx = blockIdx.x * 256 + tid;        // float4 index, exact grid
    const int n = idx >> 3;
    const float w = expf(scores[n] - M) / S;
    float4* p = reinterpret_cast<float4*>(out);
    float4 v = p[idx];
    v.x = fmaxf(v.x * w, 0.f);
    v.y = fmaxf(v.y * w, 0.f);
    v.z = fmaxf(v.z * w, 0.f);
    v.w = fmaxf(v.w * w, 0.f);
    p[idx] = v;
}

extern "C" void kernel_launch(void* const* d_in, const int* in_sizes, int n_in,
                              void* d_out, int out_size, void* d_ws, size_t ws_size,
                              hipStream_t stream) {
    const float* x   = (const float*)d_in[0];
    const int*   ei  = (const int*)  d_in[1];
    const int*   et  = (const int*)  d_in[2];
    const float* W   = (const float*)d_in[3];
    const float* rel = (const float*)d_in[4];
    const float* att = (const float*)d_in[5];
    float* out = (float*)d_out;

    // ws layout: wr[16*1024] | rec[NE int2] | cnt[16] | cursor[16]
    //            | pmax[512] | psum[512];  scores overlays rec after k_edge
    float* wr     = (float*)d_ws;
    int2*  rec    = (int2*)(wr + NR * D * D);
    int*   cnt    = (int*)(rec + NE);
    int*   cursor = cnt + NR;
    float* pmax   = (float*)(cursor + NR);
    float* psum   = pmax + 512;
    float* scores = (float*)rec;

    hipMemsetAsync(cnt, 0, 2 * NR * sizeof(int), stream);   // cnt + cursor

    const int nb_n = (NN + 255) / 256;           // 391
    k_pre<<<HB + 1, 256, 0, stream>>>(et, W, rel, wr, cnt, out);
    k_scatter<<<HB, 256, 0, stream>>>(ei, et, cnt, cursor, rec);
    k_edge<<<NR * NY, 256, 0, stream>>>(x, rec, cnt, wr, out);
    k_score<<<nb_n, 256, 0, stream>>>(out, att, scores, pmax, psum);
    k_final<<<(NN * (D / 4)) / 256, 256, 0, stream>>>(out, scores, pmax, psum, nb_n);
}

// Round 10
// 138.384 us; speedup vs baseline: 6.6173x; 1.2338x over previous
//
#include <hip/hip_runtime.h>

static constexpr int NN = 100000;   // nodes
static constexpr int NE = 500000;   // edges
static constexpr int D  = 32;       // channels
static constexpr int NR = 16;       // relations
static constexpr int HB = 256;      // histogram / scatter blocks
static constexpr int ES = (NE + HB - 1) / HB;   // edges per hist/scatter block
static constexpr int NY = 128;      // chunk blocks per type -> 2048 blocks

// ---------------- K1: zero d_out + edge-type histogram + WR = W @ R_t ----
__global__ __launch_bounds__(256) void k_pre(const int* __restrict__ et,
                                             const float* __restrict__ W,
                                             const float* __restrict__ rel,
                                             float* __restrict__ wr,
                                             int* __restrict__ cnt,
                                             float* __restrict__ outz) {
    __shared__ int lh[NR];
    if (threadIdx.x < NR) lh[threadIdx.x] = 0;
    __syncthreads();

    {   // zero d_out (grid-stride)
        float4* oz = reinterpret_cast<float4*>(outz);
        const int total4 = NN * D / 4;
        for (int i = blockIdx.x * 256 + threadIdx.x; i < total4; i += gridDim.x * 256)
            oz[i] = make_float4(0.f, 0.f, 0.f, 0.f);
    }

    if (blockIdx.x < HB) {
        const int beg = blockIdx.x * ES, end = min(beg + ES, NE);
        for (int e = beg + (int)threadIdx.x; e < end; e += 256)
            atomicAdd(&lh[et[e]], 1);
    } else {
        // WR[t][i][o] = sum_j W[i][j] * rel[t][j][o]   (msg = x @ WR_t)
        for (int idx = threadIdx.x; idx < NR * D * D; idx += 256) {
            const int t = idx >> 10;
            const int i = (idx >> 5) & 31;
            const int o = idx & 31;
            const float* Wr = W + i * D;
            const float* Rr = rel + t * (D * D) + o;
            float s = 0.f;
            #pragma unroll
            for (int j = 0; j < D; ++j)
                s = fmaf(Wr[j], Rr[j * D], s);
            wr[idx] = s;
        }
    }
    __syncthreads();
    if (blockIdx.x < HB && threadIdx.x < NR && lh[threadIdx.x] > 0)
        atomicAdd(&cnt[threadIdx.x], lh[threadIdx.x]);
}

// ---------------- K2a: scatter into type buckets (range-grab) -----------
__global__ __launch_bounds__(256) void k_scatter(const int* __restrict__ ei,
                                                 const int* __restrict__ et,
                                                 const int* __restrict__ cnt,
                                                 int* __restrict__ cursor,
                                                 int2* __restrict__ rec) {
    __shared__ int lh[NR], lcur[NR], soff[NR];
    if (threadIdx.x < NR) lh[threadIdx.x] = 0;
    if (threadIdx.x == 0) {
        int s = 0;
        for (int t = 0; t < NR; ++t) { soff[t] = s; s += cnt[t]; }
    }
    __syncthreads();
    const int beg = blockIdx.x * ES, end = min(beg + ES, NE);
    for (int e = beg + (int)threadIdx.x; e < end; e += 256)
        atomicAdd(&lh[et[e]], 1);
    __syncthreads();
    if (threadIdx.x < NR)
        lcur[threadIdx.x] = (lh[threadIdx.x] > 0)
                          ? soff[threadIdx.x] + atomicAdd(&cursor[threadIdx.x], lh[threadIdx.x])
                          : 0;
    __syncthreads();
    for (int e = beg + (int)threadIdx.x; e < end; e += 256) {
        const int t = et[e];
        const int pos = atomicAdd(&lcur[t], 1);
        rec[pos] = make_int2(ei[e], ei[NE + e]);
    }
}

// ---------------- K2b: per-edge matvec + scatter-add --------------------
// Round-6 compute core (half-wave per edge, 2-addr uniform b128 broadcast,
// R column in VGPRs) + WR fold + float4 gather (8-edge groups, 1 global
// b128 + 1 ds_write_b128 per 8 edges) + 2-deep register pipeline: rec
// prefetched 3 groups ahead, x-row 1 group ahead.
__global__ __launch_bounds__(256) void k_edge(const float* __restrict__ x,
                                              const int2* __restrict__ rec,
                                              const int* __restrict__ cnt,
                                              const float* __restrict__ wr,
                                              float* __restrict__ acc) {
    const int t    = blockIdx.x & (NR - 1);
    const int c    = blockIdx.x >> 4;          // 0..NY-1
    const int lane = threadIdx.x & 63;
    const int wv   = threadIdx.x >> 6;         // wave 0..3
    const int half = lane >> 5;                // 0/1
    const int o    = lane & 31;                // output channel
    const int r8   = lane >> 3;                // gather row 0..7
    const int q8   = lane & 7;                 // gather quad 0..7

    __shared__ float sx[4][2][8][36];          // 9216 B, row pad 36 (bank-even)
    __shared__ int   sd[4][2][8];

    float Rc[32];
    {
        const float* __restrict__ Rt = wr + t * 1024;
        #pragma unroll
        for (int i = 0; i < 32; ++i) Rc[i] = Rt[i * 32 + o];
    }

    int beg = 0;
    #pragma unroll
    for (int u = 0; u < NR; ++u) beg += (u < t) ? cnt[u] : 0;
    const int cntt = cnt[t];
    if (cntt <= 0) return;
    const int elast = beg + cntt - 1;
    const int ngrp  = (cntt + 7) >> 3;         // 8-edge groups
    const int nw    = NY * 4;                  // waves per type
    const int wid   = c * 4 + wv;
    if (wid >= ngrp) return;                   // no barriers below: safe

    // prologue prefetch (all indices clamped -> safe reads)
    int2 rr0 = rec[min(beg + wid * 8 + r8, elast)];
    int2 rr1 = rec[min(beg + (wid + nw) * 8 + r8, elast)];
    int2 rr2 = rec[min(beg + (wid + 2 * nw) * 8 + r8, elast)];
    float4 xv0 = reinterpret_cast<const float4*>(x + (size_t)rr0.x * D)[q8];

    int buf = 0;
    for (int grp = wid; grp < ngrp; grp += nw) {
        // stage current group into LDS
        *reinterpret_cast<float4*>(&sx[wv][buf][r8][q8 * 4]) = xv0;
        if (q8 == 0) sd[wv][buf][r8] = rr0.y;

        // prefetch next group's x-row and group+3's rec
        float4 xv1 = reinterpret_cast<const float4*>(x + (size_t)rr1.x * D)[q8];
        int2 rr3 = rec[min(beg + (grp + 3 * nw) * 8 + r8, elast)];

        __asm__ volatile("s_waitcnt lgkmcnt(0)" ::: "memory");

        const int lbase = grp * 8;
        #pragma unroll
        for (int jj = 0; jj < 4; ++jj) {
            const int row = jj * 2 + half;     // halves read different rows:
            const float* rp = &sx[wv][buf][row][0];   // 2-addr broadcast, free
            float p = 0.f;
            #pragma unroll
            for (int q = 0; q < 8; ++q) {
                const float4 v = *reinterpret_cast<const float4*>(rp + q * 4);
                p = fmaf(v.x, Rc[4*q+0], p);
                p = fmaf(v.y, Rc[4*q+1], p);
                p = fmaf(v.z, Rc[4*q+2], p);
                p = fmaf(v.w, Rc[4*q+3], p);
            }
            if (lbase + row < cntt) {
                const int dd = sd[wv][buf][row];
                atomicAdd(acc + (size_t)dd * D + o, p);
            }
        }
        rr0 = rr1; rr1 = rr2; rr2 = rr3; xv0 = xv1;
        buf ^= 1;
    }
}

// ---------------- K3a: scores + per-block online (max, sum-exp) ---------
__global__ __launch_bounds__(256) void k_score(const float* __restrict__ acc,
                                               const float* __restrict__ att,
                                               float* __restrict__ scores,
                                               float* __restrict__ pmax,
                                               float* __restrict__ psum) {
    __shared__ float sA[D];
    __shared__ float shm[4], shs[4];
    if (threadIdx.x < D) sA[threadIdx.x] = att[threadIdx.x];
    __syncthreads();
    const int n = blockIdx.x * 256 + threadIdx.x;
    float s = -3.4e38f;
    if (n < NN) {
        const float4* av = reinterpret_cast<const float4*>(acc + (size_t)n * D);
        float v0 = 0.f;
        #pragma unroll
        for (int k = 0; k < 8; ++k) {
            float4 v = av[k];
            v0 += v.x * sA[4*k+0] + v.y * sA[4*k+1] + v.z * sA[4*k+2] + v.w * sA[4*k+3];
        }
        scores[n] = v0;
        s = v0;
    }
    float m = s;
    #pragma unroll
    for (int offt = 32; offt > 0; offt >>= 1)
        m = fmaxf(m, __shfl_down(m, offt, 64));
    if ((threadIdx.x & 63) == 0) shm[threadIdx.x >> 6] = m;
    __syncthreads();
    const float bm = fmaxf(fmaxf(shm[0], shm[1]), fmaxf(shm[2], shm[3]));
    float e = (n < NN) ? expf(s - bm) : 0.f;
    #pragma unroll
    for (int offt = 32; offt > 0; offt >>= 1)
        e += __shfl_down(e, offt, 64);
    if ((threadIdx.x & 63) == 0) shs[threadIdx.x >> 6] = e;
    __syncthreads();
    if (threadIdx.x == 0) {
        pmax[blockIdx.x] = bm;
        psum[blockIdx.x] = shs[0] + shs[1] + shs[2] + shs[3];
    }
}

// ---------------- K3b: fused combine + scale ----------------------------
__global__ __launch_bounds__(256) void k_final(float* __restrict__ out,
                                               const float* __restrict__ scores,
                                               const float* __restrict__ pmax,
                                               const float* __restrict__ psum,
                                               int nb) {
    __shared__ float shm[4], shs[4];
    const int tid = threadIdx.x;
    float m = -3.4e38f, s = 0.f;
    for (int i = tid; i < nb; i += 256) {
        const float mi = pmax[i], si = psum[i];
        const float M = fmaxf(m, mi);
        s = s * expf(m - M) + si * expf(mi - M);
        m = M;
    }
    #pragma unroll
    for (int offt = 32; offt > 0; offt >>= 1) {
        const float mo = __shfl_down(m, offt, 64);
        const float so = __shfl_down(s, offt, 64);
        const float M = fmaxf(m, mo);
        s = s * expf(m - M) + so * expf(mo - M);
        m = M;
    }
    if ((tid & 63) == 0) { shm[tid >> 6] = m; shs[tid >> 6] = s; }
    __syncthreads();
    float M = shm[0], S = shs[0];
    #pragma unroll
    for (int w = 1; w < 4; ++w) {
        const float Mn = fmaxf(M, shm[w]);
        S = S * expf(M - Mn) + shs[w] * expf(shm[w] - Mn);
        M = Mn;
    }
    const int idx = blockIdx.x * 256 + tid;        // float4 index, exact grid
    const int n = idx >> 3;
    const float w = expf(scores[n] - M) / S;
    float4* p = reinterpret_cast<float4*>(out);
    float4 v = p[idx];
    v.x = fmaxf(v.x * w, 0.f);
    v.y = fmaxf(v.y * w, 0.f);
    v.z = fmaxf(v.z * w, 0.f);
    v.w = fmaxf(v.w * w, 0.f);
    p[idx] = v;
}

extern "C" void kernel_launch(void* const* d_in, const int* in_sizes, int n_in,
                              void* d_out, int out_size, void* d_ws, size_t ws_size,
                              hipStream_t stream) {
    const float* x   = (const float*)d_in[0];
    const int*   ei  = (const int*)  d_in[1];
    const int*   et  = (const int*)  d_in[2];
    const float* W   = (const float*)d_in[3];
    const float* rel = (const float*)d_in[4];
    const float* att = (const float*)d_in[5];
    float* out = (float*)d_out;

    // ws layout: wr[16*1024] | rec[NE int2] | cnt[16] | cursor[16]
    //            | pmax[512] | psum[512];  scores overlays rec after k_edge
    float* wr     = (float*)d_ws;
    int2*  rec    = (int2*)(wr + NR * D * D);
    int*   cnt    = (int*)(rec + NE);
    int*   cursor = cnt + NR;
    float* pmax   = (float*)(cursor + NR);
    float* psum   = pmax + 512;
    float* scores = (float*)rec;

    hipMemsetAsync(cnt, 0, 2 * NR * sizeof(int), stream);   // cnt + cursor

    const int nb_n = (NN + 255) / 256;           // 391
    k_pre<<<HB + 1, 256, 0, stream>>>(et, W, rel, wr, cnt, out);
    k_scatter<<<HB, 256, 0, stream>>>(ei, et, cnt, cursor, rec);
    k_edge<<<NR * NY, 256, 0, stream>>>(x, rec, cnt, wr, out);
    k_score<<<nb_n, 256, 0, stream>>>(out, att, scores, pmax, psum);
    k_final<<<(NN * (D / 4)) / 256, 256, 0, stream>>>(out, scores, pmax, psum, nb_n);
}